// Round 6
// baseline (224.982 us; speedup 1.0000x reference)
//
#include <hip/hip_runtime.h>
#include <hip/hip_bf16.h>
#include <math.h>

#define M_NODES 50000
#define K_NBR   16
#define DIM     256
#define H_HEADS 8
#define EPS     1e-5f
#define INV_SCALE 0.17677669529663687f  // 1/sqrt(32)

typedef __attribute__((ext_vector_type(8))) short short8;
typedef __attribute__((ext_vector_type(4))) float f32x4;
typedef __attribute__((ext_vector_type(4))) unsigned short ushort4v;

__device__ __forceinline__ unsigned short f2bf(float f) {
    unsigned x = __float_as_uint(f);
    x += 0x7FFFu + ((x >> 16) & 1u);          // round-to-nearest-even
    return (unsigned short)(x >> 16);
}
__device__ __forceinline__ float bflo(unsigned int u) {   // low bf16 of dword
    return __uint_as_float(u << 16);
}
__device__ __forceinline__ float bfhi(unsigned int u) {   // high bf16 of dword
    return __uint_as_float(u & 0xFFFF0000u);
}
__device__ __forceinline__ float sigmoidf_(float x) {
    return 1.0f / (1.0f + __expf(-x));
}

// ---------------------------------------------------------------------------
// Kernel 0: convert h -> bf16; build transposed bf16 weights:
//   WqkT[n][k] = (n<256 ? Wq[k][n] : Wk[k][n-256]),  WoT[n][k] = Wo[k][n]
// ---------------------------------------------------------------------------
__global__ __launch_bounds__(256) void prep_kernel(
    const float* __restrict__ h, const float* __restrict__ Wq,
    const float* __restrict__ Wk, const float* __restrict__ Wo,
    unsigned short* __restrict__ hb, unsigned short* __restrict__ WqkT,
    unsigned short* __restrict__ WoT)
{
    const int NH4 = M_NODES * DIM / 4;  // 3,200,000 float4 groups
    int i = blockIdx.x * 256 + threadIdx.x;
    if (i < NH4) {
        float4 v = reinterpret_cast<const float4*>(h)[i];
        ushort4v o;
        o.x = f2bf(v.x); o.y = f2bf(v.y); o.z = f2bf(v.z); o.w = f2bf(v.w);
        reinterpret_cast<ushort4v*>(hb)[i] = o;
    } else if (i < NH4 + 512 * 256) {
        int j = i - NH4; int n = j >> 8, k = j & 255;
        float v = (n < 256) ? Wq[k * 256 + n] : Wk[k * 256 + (n - 256)];
        WqkT[j] = f2bf(v);
    } else if (i < NH4 + 512 * 256 + 256 * 256) {
        int j = i - NH4 - 512 * 256; int n = j >> 8, k = j & 255;
        WoT[j] = f2bf(Wo[k * 256 + n]);
    }
}

// ---------------------------------------------------------------------------
// GEMM QK: [Q|K] = hb @ WqkT^T + [bq|bk], bf16 out split at col 256.
// 128x128 tile, 4 waves (2x2), each wave 64x64 = 4x4 frags of 16x16x32 bf16.
// LDS tiles XOR-swizzled (row&7)<<4 against 256B-stride bank conflicts.
// ---------------------------------------------------------------------------
__global__ __launch_bounds__(256) void gemm_qk_kernel(
    const unsigned short* __restrict__ A,
    const unsigned short* __restrict__ Bt,
    const float* __restrict__ bias0, const float* __restrict__ bias1,
    unsigned short* __restrict__ o_bf0, unsigned short* __restrict__ o_bf1)
{
    __shared__ __align__(16) char sA[128 * 256];
    __shared__ __align__(16) char sB[128 * 256];
    const int m0 = blockIdx.x * 128;
    const int n0 = blockIdx.y * 128;
    const int t = threadIdx.x;
    const int lane = t & 63;
    const int w = t >> 6;
    const int wr = w >> 1, wc = w & 1;

    f32x4 acc[4][4];
#pragma unroll
    for (int a = 0; a < 4; ++a)
#pragma unroll
        for (int b = 0; b < 4; ++b) acc[a][b] = (f32x4){0.f, 0.f, 0.f, 0.f};

    const char* Ab = (const char*)A;
    const char* Bb = (const char*)Bt;

    for (int kt = 0; kt < 512; kt += 256) {  // byte offset within 512B rows
#pragma unroll
        for (int i = 0; i < 8; ++i) {
            int o = i * 4096 + t * 16;
            int srow = o >> 8;
            int scol = o & 255;
            int lo = o ^ ((srow & 7) << 4);
            int ga = m0 + srow; ga = (ga < M_NODES) ? ga : (M_NODES - 1);
            short8 va = *reinterpret_cast<const short8*>(Ab + (size_t)ga * 512 + kt + scol);
            *reinterpret_cast<short8*>(sA + lo) = va;
            int gb = n0 + srow;
            short8 vb = *reinterpret_cast<const short8*>(Bb + (size_t)gb * 512 + kt + scol);
            *reinterpret_cast<short8*>(sB + lo) = vb;
        }
        __syncthreads();
#pragma unroll
        for (int ks = 0; ks < 4; ++ks) {
            const int kb = ks * 64 + (lane >> 4) * 16;
            short8 af[4], bfr[4];
#pragma unroll
            for (int mi = 0; mi < 4; ++mi) {
                int row = wr * 64 + mi * 16 + (lane & 15);
                af[mi] = *reinterpret_cast<const short8*>(
                    sA + ((row << 8) | (kb ^ ((row & 7) << 4))));
            }
#pragma unroll
            for (int ni = 0; ni < 4; ++ni) {
                int row = wc * 64 + ni * 16 + (lane & 15);
                bfr[ni] = *reinterpret_cast<const short8*>(
                    sB + ((row << 8) | (kb ^ ((row & 7) << 4))));
            }
#pragma unroll
            for (int mi = 0; mi < 4; ++mi)
#pragma unroll
                for (int ni = 0; ni < 4; ++ni)
                    acc[mi][ni] = __builtin_amdgcn_mfma_f32_16x16x32_bf16(
                        af[mi], bfr[ni], acc[mi][ni], 0, 0, 0);
        }
        __syncthreads();
    }

#pragma unroll
    for (int ni = 0; ni < 4; ++ni) {
        int gcol = n0 + wc * 64 + ni * 16 + (lane & 15);
        float bias = (gcol < 256) ? bias0[gcol] : bias1[gcol - 256];
#pragma unroll
        for (int mi = 0; mi < 4; ++mi) {
#pragma unroll
            for (int q = 0; q < 4; ++q) {
                int grow = m0 + wr * 64 + mi * 16 + (lane >> 4) * 4 + q;
                if (grow < M_NODES) {
                    float v = acc[mi][ni][q] + bias;
                    if (gcol < 256) o_bf0[(size_t)grow * 256 + gcol] = f2bf(v);
                    else            o_bf1[(size_t)grow * 256 + (gcol - 256)] = f2bf(v);
                }
            }
        }
    }
}

// ---------------------------------------------------------------------------
// Attention: ONE WAVE per node, SINGLE PASS over kv slots (online weighted
// accumulation). Key insight: sigmoid outputs are in (0,1), so the softmax
// max-shift is unnecessary for fp32 stability (exp(v) in [1,e]) and cancels
// exactly. Thus slot s needs kv_s live only within its own iteration:
//   e_s = exp(masked sigmoid(dot_s/scale));  ctx += e_s*kv_s;  wsum += e_s
// No kf[16]/p[16] arrays, no second gather, no uniform branches (clamped
// row + packed cndmask keeps all 16 loads unconditional and pipelineable).
// ---------------------------------------------------------------------------
__global__ __launch_bounds__(256) void attn_kernel(
    const float* __restrict__ h,
    const int* __restrict__ nbr_idx,
    const void* __restrict__ nbr_mask_raw,
    const unsigned short* __restrict__ Qb,
    const unsigned short* __restrict__ Kb,
    const float* __restrict__ bk,
    unsigned short* __restrict__ Ctxb)
{
    const int wid  = threadIdx.x >> 6;
    const int lane = threadIdx.x & 63;
    const int n    = blockIdx.x * 4 + wid;

    // ---- mask dtype detect: lane l inspects word l of first 256 bytes ----
    const unsigned int* mw = (const unsigned int*)nbr_mask_raw;
    unsigned long long det = __ballot((mw[lane] & 0xFFFFFF00u) != 0u);
    const bool is_byte = (det != 0ull);

    // ---- per-node mask bits + neighbor idx (lanes 0..15) ----
    unsigned int mbit = 0;
    int idxv = 0;
    if (lane < K_NBR) {
        if (is_byte) mbit = ((const unsigned char*)nbr_mask_raw)[n * K_NBR + lane] ? 1u : 0u;
        else         mbit = ((const int*)nbr_mask_raw)[n * K_NBR + lane] ? 1u : 0u;
        idxv = nbr_idx[n * K_NBR + lane];
    }
    unsigned long long bal = __ballot(mbit != 0u);
    const unsigned int mask16 = (unsigned int)(bal & 0xFFFFull);

    // ---- coalesced per-node loads ----
    const float4 h4 = *reinterpret_cast<const float4*>(h + (size_t)n * DIM + 4 * lane);
    const uint2  qp = *reinterpret_cast<const uint2*>(Qb + (size_t)n * DIM + 4 * lane);
    const float4 b4 = *reinterpret_cast<const float4*>(bk + 4 * lane);
    uint2 bkp;
    bkp.x = (unsigned)f2bf(b4.x) | ((unsigned)f2bf(b4.y) << 16);
    bkp.y = (unsigned)f2bf(b4.z) | ((unsigned)f2bf(b4.w) << 16);

    // ---- compacted row list (VGPR; -1 when exhausted) ----
    int rows[K_NBR];
    unsigned int mm = mask16;
#pragma unroll
    for (int s = 0; s < K_NBR; ++s) {
        int j = __ffs(mm) - 1;                 // wave-uniform
        int r = __shfl(idxv, (j < 0) ? 0 : j, 64);
        rows[s] = (j >= 0) ? r : -1;
        mm &= mm - 1;
    }

    const float q0 = bflo(qp.x), q1 = bfhi(qp.x), q2 = bflo(qp.y), q3 = bfhi(qp.y);

    // ---- single pass: dot -> weight -> accumulate ----
    float c0 = 0.f, c1 = 0.f, c2 = 0.f, c3 = 0.f, wsum = 0.f;
#pragma unroll
    for (int s = 0; s < K_NBR; ++s) {
        const int rclamp = (rows[s] >= 0) ? rows[s] : 0;
        uint2 kp = *reinterpret_cast<const uint2*>(Kb + (size_t)rclamp * DIM + 4 * lane);
        kp.x = (rows[s] >= 0) ? kp.x : bkp.x;   // padded slot -> bias row
        kp.y = (rows[s] >= 0) ? kp.y : bkp.y;
        const float k0 = bflo(kp.x), k1 = bfhi(kp.x);
        const float k2 = bflo(kp.y), k3 = bfhi(kp.y);

        float a = q0 * k0 + q1 * k1 + q2 * k2 + q3 * k3;
        a += __shfl_xor(a, 1, 8);
        a += __shfl_xor(a, 2, 8);
        a += __shfl_xor(a, 4, 8);               // full 32-dim dot, head = lane>>3

        float v = ((mask16 >> s) & 1u) ? sigmoidf_(a * INV_SCALE) : 0.0f;
        float e = __expf(v);                    // no max-shift needed: v in [0,1]
        c0 = fmaf(e, k0, c0);
        c1 = fmaf(e, k1, c1);
        c2 = fmaf(e, k2, c2);
        c3 = fmaf(e, k3, c3);
        wsum += e;
    }
    const float inv = 1.0f / wsum;

    const float r0 = h4.x + c0 * inv;
    const float r1 = h4.y + c1 * inv;
    const float r2 = h4.z + c2 * inv;
    const float r3 = h4.w + c3 * inv;

    uint2 o;
    o.x = (unsigned)f2bf(r0) | ((unsigned)f2bf(r1) << 16);
    o.y = (unsigned)f2bf(r2) | ((unsigned)f2bf(r3) << 16);
    *reinterpret_cast<uint2*>(Ctxb + (size_t)n * DIM + 4 * lane) = o;
}

// ---------------------------------------------------------------------------
// Output GEMM fused with LayerNorm. 512 threads = 8 waves (2 row x 4 col),
// tile 128 rows x 256 cols (full row width per block), K in 4 chunks of 64.
// Row mean/var: per-wave 16-lane swizzle reduce -> 4KB LDS cross-wave
// combine -> normalize directly from accumulators.
// ---------------------------------------------------------------------------
__global__ __launch_bounds__(512) void gemm_out_ln_kernel(
    const unsigned short* __restrict__ A,    // Ctx bf16 [M][256]
    const unsigned short* __restrict__ Bt,   // WoT bf16 [256][256]
    const float* __restrict__ bo,
    const float* __restrict__ gamma, const float* __restrict__ beta,
    float* __restrict__ out)
{
    __shared__ __align__(16) char sA[128 * 128];   // 16 KB (128 rows x 128B)
    __shared__ __align__(16) char sB[256 * 128];   // 32 KB
    __shared__ float part[4][128][2];              // per-wc row partials
    __shared__ float muinv[128][2];
    const int m0 = blockIdx.x * 128;
    const int t = threadIdx.x;
    const int lane = t & 63;
    const int w = t >> 6;            // 0..7
    const int wr = w >> 2, wc = w & 3;

    f32x4 acc[4][4];
#pragma unroll
    for (int a = 0; a < 4; ++a)
#pragma unroll
        for (int b = 0; b < 4; ++b) acc[a][b] = (f32x4){0.f, 0.f, 0.f, 0.f};

    const char* Ab = (const char*)A;
    const char* Bb = (const char*)Bt;

    for (int kt = 0; kt < 512; kt += 128) {   // 4 K-chunks of 64 elems (128B)
#pragma unroll
        for (int i = 0; i < 2; ++i) {         // stage A: 16 KB
            int o = i * 8192 + t * 16;
            int row = o >> 7, col = o & 127;
            int lo = o ^ ((row & 7) << 4);
            int ga = m0 + row; ga = (ga < M_NODES) ? ga : (M_NODES - 1);
            short8 va = *reinterpret_cast<const short8*>(Ab + (size_t)ga * 512 + kt + col);
            *reinterpret_cast<short8*>(sA + lo) = va;
        }
#pragma unroll
        for (int i = 0; i < 4; ++i) {         // stage B: 32 KB
            int o = i * 8192 + t * 16;
            int row = o >> 7, col = o & 127;
            int lo = o ^ ((row & 7) << 4);
            short8 vb = *reinterpret_cast<const short8*>(Bb + (size_t)row * 512 + kt + col);
            *reinterpret_cast<short8*>(sB + lo) = vb;
        }
        __syncthreads();
#pragma unroll
        for (int ks = 0; ks < 2; ++ks) {
            const int kb = ks * 64 + (lane >> 4) * 16;
            short8 af[4], bfr[4];
#pragma unroll
            for (int mi = 0; mi < 4; ++mi) {
                int row = wr * 64 + mi * 16 + (lane & 15);
                af[mi] = *reinterpret_cast<const short8*>(
                    sA + ((row << 7) | (kb ^ ((row & 7) << 4))));
            }
#pragma unroll
            for (int ni = 0; ni < 4; ++ni) {
                int row = wc * 64 + ni * 16 + (lane & 15);
                bfr[ni] = *reinterpret_cast<const short8*>(
                    sB + ((row << 7) | (kb ^ ((row & 7) << 4))));
            }
#pragma unroll
            for (int mi = 0; mi < 4; ++mi)
#pragma unroll
                for (int ni = 0; ni < 4; ++ni)
                    acc[mi][ni] = __builtin_amdgcn_mfma_f32_16x16x32_bf16(
                        af[mi], bfr[ni], acc[mi][ni], 0, 0, 0);
        }
        __syncthreads();
    }

    // ---- LN stats: per-row sum/sumsq ----
    float bias4[4];
#pragma unroll
    for (int ni = 0; ni < 4; ++ni) bias4[ni] = bo[wc * 64 + ni * 16 + (lane & 15)];

#pragma unroll
    for (int mi = 0; mi < 4; ++mi) {
#pragma unroll
        for (int q = 0; q < 4; ++q) {
            float s = 0.f, sq = 0.f;
#pragma unroll
            for (int ni = 0; ni < 4; ++ni) {
                float v = acc[mi][ni][q] + bias4[ni];
                s += v; sq += v * v;
            }
            s  += __shfl_xor(s, 1, 16);  sq += __shfl_xor(sq, 1, 16);
            s  += __shfl_xor(s, 2, 16);  sq += __shfl_xor(sq, 2, 16);
            s  += __shfl_xor(s, 4, 16);  sq += __shfl_xor(sq, 4, 16);
            s  += __shfl_xor(s, 8, 16);  sq += __shfl_xor(sq, 8, 16);
            int lrow = wr * 64 + mi * 16 + (lane >> 4) * 4 + q;
            if ((lane & 15) == 0) { part[wc][lrow][0] = s; part[wc][lrow][1] = sq; }
        }
    }
    __syncthreads();
    if (t < 128) {
        float s  = part[0][t][0] + part[1][t][0] + part[2][t][0] + part[3][t][0];
        float sq = part[0][t][1] + part[1][t][1] + part[2][t][1] + part[3][t][1];
        float mu  = s * (1.f / 256.f);
        float var = sq * (1.f / 256.f) - mu * mu;
        muinv[t][0] = mu;
        muinv[t][1] = rsqrtf(var + EPS);
    }
    __syncthreads();

    // ---- normalize + store ----
    float g4[4], be4[4];
#pragma unroll
    for (int ni = 0; ni < 4; ++ni) {
        int gcol = wc * 64 + ni * 16 + (lane & 15);
        g4[ni] = gamma[gcol];
        be4[ni] = beta[gcol];
    }
#pragma unroll
    for (int mi = 0; mi < 4; ++mi) {
#pragma unroll
        for (int q = 0; q < 4; ++q) {
            int lrow = wr * 64 + mi * 16 + (lane >> 4) * 4 + q;
            int grow = m0 + lrow;
            float mu  = muinv[lrow][0];
            float inv = muinv[lrow][1];
            if (grow < M_NODES) {
#pragma unroll
                for (int ni = 0; ni < 4; ++ni) {
                    int gcol = wc * 64 + ni * 16 + (lane & 15);
                    float v = acc[mi][ni][q] + bias4[ni];
                    out[(size_t)grow * 256 + gcol] = (v - mu) * inv * g4[ni] + be4[ni];
                }
            }
        }
    }
}

// ---------------------------------------------------------------------------
extern "C" void kernel_launch(void* const* d_in, const int* in_sizes, int n_in,
                              void* d_out, int out_size, void* d_ws, size_t ws_size,
                              hipStream_t stream) {
    const float* h       = (const float*)d_in[0];
    const int* nbr_idx   = (const int*)d_in[1];
    const void* nbr_mask = (const void*)d_in[2];
    const float* Wq_w    = (const float*)d_in[3];
    const float* Wq_b    = (const float*)d_in[4];
    const float* Wk_w    = (const float*)d_in[5];
    const float* Wk_b    = (const float*)d_in[6];
    const float* Wo_w    = (const float*)d_in[7];
    const float* Wo_b    = (const float*)d_in[8];
    const float* gamma   = (const float*)d_in[9];
    const float* beta    = (const float*)d_in[10];
    float* out = (float*)d_out;

    // ws layout (bytes): [Qb/Ctxb 25.6M][Kb 25.6M][hb 25.6M][WqkT 256K][WoT 128K]
    char* ws = (char*)d_ws;
    unsigned short* Qb   = (unsigned short*)(ws);
    unsigned short* Kb   = (unsigned short*)(ws + 25600000);
    unsigned short* hb   = (unsigned short*)(ws + 51200000);
    unsigned short* WqkT = (unsigned short*)(ws + 76800000);
    unsigned short* WoT  = (unsigned short*)(ws + 77062144);

    hipLaunchKernelGGL(prep_kernel, dim3(13268), dim3(256), 0, stream,
                       h, Wq_w, Wk_w, Wo_w, hb, WqkT, WoT);
    hipLaunchKernelGGL(gemm_qk_kernel, dim3(391, 4), dim3(256), 0, stream,
                       hb, WqkT, Wq_b, Wk_b, Qb, Kb);
    hipLaunchKernelGGL(attn_kernel, dim3(12500), dim3(256), 0, stream,
                       h, nbr_idx, nbr_mask, Qb, Kb, Wk_b, Qb /*Ctx aliases Q*/);
    hipLaunchKernelGGL(gemm_out_ln_kernel, dim3(391), dim3(512), 0, stream,
                       Qb /*Ctx*/, WoT, Wo_b, gamma, beta, out);
}

// Round 7
// 186.197 us; speedup vs baseline: 1.2083x; 1.2083x over previous
//
#include <hip/hip_runtime.h>
#include <hip/hip_bf16.h>
#include <math.h>

#define M_NODES 50000
#define K_NBR   16
#define DIM     256
#define H_HEADS 8
#define EPS     1e-5f
#define INV_SCALE 0.17677669529663687f  // 1/sqrt(32)

typedef __attribute__((ext_vector_type(8))) short short8;
typedef __attribute__((ext_vector_type(4))) float f32x4;
typedef __attribute__((ext_vector_type(4))) unsigned short ushort4v;

__device__ __forceinline__ unsigned short f2bf(float f) {
    unsigned x = __float_as_uint(f);
    x += 0x7FFFu + ((x >> 16) & 1u);          // round-to-nearest-even
    return (unsigned short)(x >> 16);
}
__device__ __forceinline__ float bflo(unsigned int u) {   // low bf16 of dword
    return __uint_as_float(u << 16);
}
__device__ __forceinline__ float bfhi(unsigned int u) {   // high bf16 of dword
    return __uint_as_float(u & 0xFFFF0000u);
}
__device__ __forceinline__ float sigmoidf_(float x) {
    return 1.0f / (1.0f + __expf(-x));
}
// async global->LDS, 16B per lane; dest = wave-uniform base + lane*16,
// source is PER-LANE (gather allowed). No dest VGPRs -> free MLP.
__device__ __forceinline__ void gload_lds16(const void* g, void* l) {
    __builtin_amdgcn_global_load_lds(
        (const __attribute__((address_space(1))) unsigned int*)g,
        (__attribute__((address_space(3))) unsigned int*)l, 16, 0, 0);
}

// ---------------------------------------------------------------------------
// Kernel 0: convert h -> bf16; build transposed bf16 weights:
//   WqkT[n][k] = (n<256 ? Wq[k][n] : Wk[k][n-256]),  WoT[n][k] = Wo[k][n]
// ---------------------------------------------------------------------------
__global__ __launch_bounds__(256) void prep_kernel(
    const float* __restrict__ h, const float* __restrict__ Wq,
    const float* __restrict__ Wk, const float* __restrict__ Wo,
    unsigned short* __restrict__ hb, unsigned short* __restrict__ WqkT,
    unsigned short* __restrict__ WoT)
{
    const int NH4 = M_NODES * DIM / 4;  // 3,200,000 float4 groups
    int i = blockIdx.x * 256 + threadIdx.x;
    if (i < NH4) {
        float4 v = reinterpret_cast<const float4*>(h)[i];
        ushort4v o;
        o.x = f2bf(v.x); o.y = f2bf(v.y); o.z = f2bf(v.z); o.w = f2bf(v.w);
        reinterpret_cast<ushort4v*>(hb)[i] = o;
    } else if (i < NH4 + 512 * 256) {
        int j = i - NH4; int n = j >> 8, k = j & 255;
        float v = (n < 256) ? Wq[k * 256 + n] : Wk[k * 256 + (n - 256)];
        WqkT[j] = f2bf(v);
    } else if (i < NH4 + 512 * 256 + 256 * 256) {
        int j = i - NH4 - 512 * 256; int n = j >> 8, k = j & 255;
        WoT[j] = f2bf(Wo[k * 256 + n]);
    }
}

// ---------------------------------------------------------------------------
// GEMM QK: [Q|K] = hb @ WqkT^T + [bq|bk], bf16 out split at col 256.
// 128x128 tile, 4 waves (2x2), each wave 64x64 = 4x4 frags of 16x16x32 bf16.
// LDS tiles XOR-swizzled (row&7)<<4 against 256B-stride bank conflicts.
// ---------------------------------------------------------------------------
__global__ __launch_bounds__(256) void gemm_qk_kernel(
    const unsigned short* __restrict__ A,
    const unsigned short* __restrict__ Bt,
    const float* __restrict__ bias0, const float* __restrict__ bias1,
    unsigned short* __restrict__ o_bf0, unsigned short* __restrict__ o_bf1)
{
    __shared__ __align__(16) char sA[128 * 256];
    __shared__ __align__(16) char sB[128 * 256];
    const int m0 = blockIdx.x * 128;
    const int n0 = blockIdx.y * 128;
    const int t = threadIdx.x;
    const int lane = t & 63;
    const int w = t >> 6;
    const int wr = w >> 1, wc = w & 1;

    f32x4 acc[4][4];
#pragma unroll
    for (int a = 0; a < 4; ++a)
#pragma unroll
        for (int b = 0; b < 4; ++b) acc[a][b] = (f32x4){0.f, 0.f, 0.f, 0.f};

    const char* Ab = (const char*)A;
    const char* Bb = (const char*)Bt;

    for (int kt = 0; kt < 512; kt += 256) {  // byte offset within 512B rows
#pragma unroll
        for (int i = 0; i < 8; ++i) {
            int o = i * 4096 + t * 16;
            int srow = o >> 8;
            int scol = o & 255;
            int lo = o ^ ((srow & 7) << 4);
            int ga = m0 + srow; ga = (ga < M_NODES) ? ga : (M_NODES - 1);
            short8 va = *reinterpret_cast<const short8*>(Ab + (size_t)ga * 512 + kt + scol);
            *reinterpret_cast<short8*>(sA + lo) = va;
            int gb = n0 + srow;
            short8 vb = *reinterpret_cast<const short8*>(Bb + (size_t)gb * 512 + kt + scol);
            *reinterpret_cast<short8*>(sB + lo) = vb;
        }
        __syncthreads();
#pragma unroll
        for (int ks = 0; ks < 4; ++ks) {
            const int kb = ks * 64 + (lane >> 4) * 16;
            short8 af[4], bfr[4];
#pragma unroll
            for (int mi = 0; mi < 4; ++mi) {
                int row = wr * 64 + mi * 16 + (lane & 15);
                af[mi] = *reinterpret_cast<const short8*>(
                    sA + ((row << 8) | (kb ^ ((row & 7) << 4))));
            }
#pragma unroll
            for (int ni = 0; ni < 4; ++ni) {
                int row = wc * 64 + ni * 16 + (lane & 15);
                bfr[ni] = *reinterpret_cast<const short8*>(
                    sB + ((row << 8) | (kb ^ ((row & 7) << 4))));
            }
#pragma unroll
            for (int mi = 0; mi < 4; ++mi)
#pragma unroll
                for (int ni = 0; ni < 4; ++ni)
                    acc[mi][ni] = __builtin_amdgcn_mfma_f32_16x16x32_bf16(
                        af[mi], bfr[ni], acc[mi][ni], 0, 0, 0);
        }
        __syncthreads();
    }

#pragma unroll
    for (int ni = 0; ni < 4; ++ni) {
        int gcol = n0 + wc * 64 + ni * 16 + (lane & 15);
        float bias = (gcol < 256) ? bias0[gcol] : bias1[gcol - 256];
#pragma unroll
        for (int mi = 0; mi < 4; ++mi) {
#pragma unroll
            for (int q = 0; q < 4; ++q) {
                int grow = m0 + wr * 64 + mi * 16 + (lane >> 4) * 4 + q;
                if (grow < M_NODES) {
                    float v = acc[mi][ni][q] + bias;
                    if (gcol < 256) o_bf0[(size_t)grow * 256 + gcol] = f2bf(v);
                    else            o_bf1[(size_t)grow * 256 + (gcol - 256)] = f2bf(v);
                }
            }
        }
    }
}

// ---------------------------------------------------------------------------
// Attention: ONE WAVE per node. Round-6 online single-pass algebra (verified)
// but the 16-row gather goes through global_load_lds DMA: 8 fire-and-forget
// instructions (each stages 2 rows: lanes 0-31 -> row s, 32-63 -> row s+1,
// per-lane source addresses), all in flight under one vmcnt drain -> MLP by
// construction, zero dest VGPRs. Each wave owns a private 8KB LDS region ->
// NO barriers. kv then read per-slot via ds_read_b64.
// ---------------------------------------------------------------------------
__global__ __launch_bounds__(256) void attn_kernel(
    const float* __restrict__ h,
    const int* __restrict__ nbr_idx,
    const void* __restrict__ nbr_mask_raw,
    const unsigned short* __restrict__ Qb,
    const unsigned short* __restrict__ Kb,
    const float* __restrict__ bk,
    unsigned short* __restrict__ Ctxb)
{
    __shared__ __align__(16) char smem[4][8192];   // 8KB per wave (16 rows x 512B)
    const int wid  = threadIdx.x >> 6;
    const int lane = threadIdx.x & 63;
    const int n    = blockIdx.x * 4 + wid;
    char* wbase = smem[wid];

    // ---- mask dtype detect: lane l inspects word l of first 256 bytes ----
    const unsigned int* mw = (const unsigned int*)nbr_mask_raw;
    unsigned long long det = __ballot((mw[lane] & 0xFFFFFF00u) != 0u);
    const bool is_byte = (det != 0ull);

    // ---- per-node mask bits + neighbor idx (lanes 0..15) ----
    unsigned int mbit = 0;
    int idxv = 0;
    if (lane < K_NBR) {
        if (is_byte) mbit = ((const unsigned char*)nbr_mask_raw)[n * K_NBR + lane] ? 1u : 0u;
        else         mbit = ((const int*)nbr_mask_raw)[n * K_NBR + lane] ? 1u : 0u;
        idxv = nbr_idx[n * K_NBR + lane];
    }
    unsigned long long bal = __ballot(mbit != 0u);
    const unsigned int mask16 = (unsigned int)(bal & 0xFFFFull);

    // ---- compacted row list (VGPR; -1 when exhausted) ----
    int rows[K_NBR];
    unsigned int mm = mask16;
#pragma unroll
    for (int s = 0; s < K_NBR; ++s) {
        int j = __ffs(mm) - 1;                 // wave-uniform
        int r = __shfl(idxv, (j < 0) ? 0 : j, 64);
        rows[s] = (j >= 0) ? r : -1;
        mm &= mm - 1;
    }

    // ---- issue all 16 row-gathers as 8 async DMA instructions ----
    const char* Kbb = (const char*)Kb;
#pragma unroll
    for (int s = 0; s < K_NBR; s += 2) {
        int rlo = (rows[s]     >= 0) ? rows[s]     : 0;
        int rhi = (rows[s + 1] >= 0) ? rows[s + 1] : 0;
        int r = (lane < 32) ? rlo : rhi;
        gload_lds16(Kbb + (size_t)r * 512 + (lane & 31) * 16, wbase + s * 512);
    }

    // ---- per-node coalesced loads (overlap with DMA) ----
    const float4 h4 = *reinterpret_cast<const float4*>(h + (size_t)n * DIM + 4 * lane);
    const uint2  qp = *reinterpret_cast<const uint2*>(Qb + (size_t)n * DIM + 4 * lane);
    const float4 b4 = *reinterpret_cast<const float4*>(bk + 4 * lane);
    uint2 bkp;
    bkp.x = (unsigned)f2bf(b4.x) | ((unsigned)f2bf(b4.y) << 16);
    bkp.y = (unsigned)f2bf(b4.z) | ((unsigned)f2bf(b4.w) << 16);
    const float q0 = bflo(qp.x), q1 = bfhi(qp.x), q2 = bflo(qp.y), q3 = bfhi(qp.y);

    // ---- drain DMA before reading LDS (wave-private region, no barrier) ----
    asm volatile("s_waitcnt vmcnt(0)" ::: "memory");

    // ---- single pass: dot -> weight -> accumulate ----
    float c0 = 0.f, c1 = 0.f, c2 = 0.f, c3 = 0.f, wsum = 0.f;
#pragma unroll
    for (int s = 0; s < K_NBR; ++s) {
        uint2 kp = *reinterpret_cast<const uint2*>(wbase + s * 512 + lane * 8);
        kp.x = (rows[s] >= 0) ? kp.x : bkp.x;   // padded slot -> bias row
        kp.y = (rows[s] >= 0) ? kp.y : bkp.y;
        const float k0 = bflo(kp.x), k1 = bfhi(kp.x);
        const float k2 = bflo(kp.y), k3 = bfhi(kp.y);

        float a = q0 * k0 + q1 * k1 + q2 * k2 + q3 * k3;
        a += __shfl_xor(a, 1, 8);
        a += __shfl_xor(a, 2, 8);
        a += __shfl_xor(a, 4, 8);               // full 32-dim dot, head = lane>>3

        float v = ((mask16 >> s) & 1u) ? sigmoidf_(a * INV_SCALE) : 0.0f;
        float e = __expf(v);                    // no max-shift needed: v in [0,1]
        c0 = fmaf(e, k0, c0);
        c1 = fmaf(e, k1, c1);
        c2 = fmaf(e, k2, c2);
        c3 = fmaf(e, k3, c3);
        wsum += e;
    }
    const float inv = 1.0f / wsum;

    const float r0 = h4.x + c0 * inv;
    const float r1 = h4.y + c1 * inv;
    const float r2 = h4.z + c2 * inv;
    const float r3 = h4.w + c3 * inv;

    uint2 o;
    o.x = (unsigned)f2bf(r0) | ((unsigned)f2bf(r1) << 16);
    o.y = (unsigned)f2bf(r2) | ((unsigned)f2bf(r3) << 16);
    *reinterpret_cast<uint2*>(Ctxb + (size_t)n * DIM + 4 * lane) = o;
}

// ---------------------------------------------------------------------------
// Output GEMM fused with LayerNorm. 512 threads = 8 waves (2 row x 4 col),
// tile 128 rows x 256 cols (full row width per block), K in 4 chunks of 64.
// Row mean/var: per-wave 16-lane swizzle reduce -> 4KB LDS cross-wave
// combine -> normalize directly from accumulators.
// ---------------------------------------------------------------------------
__global__ __launch_bounds__(512) void gemm_out_ln_kernel(
    const unsigned short* __restrict__ A,    // Ctx bf16 [M][256]
    const unsigned short* __restrict__ Bt,   // WoT bf16 [256][256]
    const float* __restrict__ bo,
    const float* __restrict__ gamma, const float* __restrict__ beta,
    float* __restrict__ out)
{
    __shared__ __align__(16) char sA[128 * 128];   // 16 KB (128 rows x 128B)
    __shared__ __align__(16) char sB[256 * 128];   // 32 KB
    __shared__ float part[4][128][2];              // per-wc row partials
    __shared__ float muinv[128][2];
    const int m0 = blockIdx.x * 128;
    const int t = threadIdx.x;
    const int lane = t & 63;
    const int w = t >> 6;            // 0..7
    const int wr = w >> 2, wc = w & 3;

    f32x4 acc[4][4];
#pragma unroll
    for (int a = 0; a < 4; ++a)
#pragma unroll
        for (int b = 0; b < 4; ++b) acc[a][b] = (f32x4){0.f, 0.f, 0.f, 0.f};

    const char* Ab = (const char*)A;
    const char* Bb = (const char*)Bt;

    for (int kt = 0; kt < 512; kt += 128) {   // 4 K-chunks of 64 elems (128B)
#pragma unroll
        for (int i = 0; i < 2; ++i) {         // stage A: 16 KB
            int o = i * 8192 + t * 16;
            int row = o >> 7, col = o & 127;
            int lo = o ^ ((row & 7) << 4);
            int ga = m0 + row; ga = (ga < M_NODES) ? ga : (M_NODES - 1);
            short8 va = *reinterpret_cast<const short8*>(Ab + (size_t)ga * 512 + kt + col);
            *reinterpret_cast<short8*>(sA + lo) = va;
        }
#pragma unroll
        for (int i = 0; i < 4; ++i) {         // stage B: 32 KB
            int o = i * 8192 + t * 16;
            int row = o >> 7, col = o & 127;
            int lo = o ^ ((row & 7) << 4);
            short8 vb = *reinterpret_cast<const short8*>(Bb + (size_t)row * 512 + kt + col);
            *reinterpret_cast<short8*>(sB + lo) = vb;
        }
        __syncthreads();
#pragma unroll
        for (int ks = 0; ks < 2; ++ks) {
            const int kb = ks * 64 + (lane >> 4) * 16;
            short8 af[4], bfr[4];
#pragma unroll
            for (int mi = 0; mi < 4; ++mi) {
                int row = wr * 64 + mi * 16 + (lane & 15);
                af[mi] = *reinterpret_cast<const short8*>(
                    sA + ((row << 7) | (kb ^ ((row & 7) << 4))));
            }
#pragma unroll
            for (int ni = 0; ni < 4; ++ni) {
                int row = wc * 64 + ni * 16 + (lane & 15);
                bfr[ni] = *reinterpret_cast<const short8*>(
                    sB + ((row << 7) | (kb ^ ((row & 7) << 4))));
            }
#pragma unroll
            for (int mi = 0; mi < 4; ++mi)
#pragma unroll
                for (int ni = 0; ni < 4; ++ni)
                    acc[mi][ni] = __builtin_amdgcn_mfma_f32_16x16x32_bf16(
                        af[mi], bfr[ni], acc[mi][ni], 0, 0, 0);
        }
        __syncthreads();
    }

    // ---- LN stats: per-row sum/sumsq ----
    float bias4[4];
#pragma unroll
    for (int ni = 0; ni < 4; ++ni) bias4[ni] = bo[wc * 64 + ni * 16 + (lane & 15)];

#pragma unroll
    for (int mi = 0; mi < 4; ++mi) {
#pragma unroll
        for (int q = 0; q < 4; ++q) {
            float s = 0.f, sq = 0.f;
#pragma unroll
            for (int ni = 0; ni < 4; ++ni) {
                float v = acc[mi][ni][q] + bias4[ni];
                s += v; sq += v * v;
            }
            s  += __shfl_xor(s, 1, 16);  sq += __shfl_xor(sq, 1, 16);
            s  += __shfl_xor(s, 2, 16);  sq += __shfl_xor(sq, 2, 16);
            s  += __shfl_xor(s, 4, 16);  sq += __shfl_xor(sq, 4, 16);
            s  += __shfl_xor(s, 8, 16);  sq += __shfl_xor(sq, 8, 16);
            int lrow = wr * 64 + mi * 16 + (lane >> 4) * 4 + q;
            if ((lane & 15) == 0) { part[wc][lrow][0] = s; part[wc][lrow][1] = sq; }
        }
    }
    __syncthreads();
    if (t < 128) {
        float s  = part[0][t][0] + part[1][t][0] + part[2][t][0] + part[3][t][0];
        float sq = part[0][t][1] + part[1][t][1] + part[2][t][1] + part[3][t][1];
        float mu  = s * (1.f / 256.f);
        float var = sq * (1.f / 256.f) - mu * mu;
        muinv[t][0] = mu;
        muinv[t][1] = rsqrtf(var + EPS);
    }
    __syncthreads();

    // ---- normalize + store ----
    float g4[4], be4[4];
#pragma unroll
    for (int ni = 0; ni < 4; ++ni) {
        int gcol = wc * 64 + ni * 16 + (lane & 15);
        g4[ni] = gamma[gcol];
        be4[ni] = beta[gcol];
    }
#pragma unroll
    for (int mi = 0; mi < 4; ++mi) {
#pragma unroll
        for (int q = 0; q < 4; ++q) {
            int lrow = wr * 64 + mi * 16 + (lane >> 4) * 4 + q;
            int grow = m0 + lrow;
            float mu  = muinv[lrow][0];
            float inv = muinv[lrow][1];
            if (grow < M_NODES) {
#pragma unroll
                for (int ni = 0; ni < 4; ++ni) {
                    int gcol = wc * 64 + ni * 16 + (lane & 15);
                    float v = acc[mi][ni][q] + bias4[ni];
                    out[(size_t)grow * 256 + gcol] = (v - mu) * inv * g4[ni] + be4[ni];
                }
            }
        }
    }
}

// ---------------------------------------------------------------------------
extern "C" void kernel_launch(void* const* d_in, const int* in_sizes, int n_in,
                              void* d_out, int out_size, void* d_ws, size_t ws_size,
                              hipStream_t stream) {
    const float* h       = (const float*)d_in[0];
    const int* nbr_idx   = (const int*)d_in[1];
    const void* nbr_mask = (const void*)d_in[2];
    const float* Wq_w    = (const float*)d_in[3];
    const float* Wq_b    = (const float*)d_in[4];
    const float* Wk_w    = (const float*)d_in[5];
    const float* Wk_b    = (const float*)d_in[6];
    const float* Wo_w    = (const float*)d_in[7];
    const float* Wo_b    = (const float*)d_in[8];
    const float* gamma   = (const float*)d_in[9];
    const float* beta    = (const float*)d_in[10];
    float* out = (float*)d_out;

    // ws layout (bytes): [Qb/Ctxb 25.6M][Kb 25.6M][hb 25.6M][WqkT 256K][WoT 128K]
    char* ws = (char*)d_ws;
    unsigned short* Qb   = (unsigned short*)(ws);
    unsigned short* Kb   = (unsigned short*)(ws + 25600000);
    unsigned short* hb   = (unsigned short*)(ws + 51200000);
    unsigned short* WqkT = (unsigned short*)(ws + 76800000);
    unsigned short* WoT  = (unsigned short*)(ws + 77062144);

    hipLaunchKernelGGL(prep_kernel, dim3(13268), dim3(256), 0, stream,
                       h, Wq_w, Wk_w, Wo_w, hb, WqkT, WoT);
    hipLaunchKernelGGL(gemm_qk_kernel, dim3(391, 4), dim3(256), 0, stream,
                       hb, WqkT, Wq_b, Wk_b, Qb, Kb);
    hipLaunchKernelGGL(attn_kernel, dim3(12500), dim3(256), 0, stream,
                       h, nbr_idx, nbr_mask, Qb, Kb, Wk_b, Qb /*Ctx aliases Q*/);
    hipLaunchKernelGGL(gemm_out_ln_kernel, dim3(391), dim3(512), 0, stream,
                       Qb /*Ctx*/, WoT, Wo_b, gamma, beta, out);
}